// Round 1
// baseline (261.503 us; speedup 1.0000x reference)
//
#include <hip/hip_runtime.h>
#include <cmath>

#define TSEQ 256
#define TMEL 1024
#define DDIM 80
#define NBATCH 64
#define NEGV (-10000.0f)

// logaddexp(x, y) = max + log1p(exp(-|x-y|)), via native exp2/log2
__device__ __forceinline__ float lae(float x, float y) {
    float m = fmaxf(x, y);
    float d = fabsf(x - y);
    float e = exp2f(d * -1.44269504f);
    float l = __log2f(1.0f + e);
    return fmaf(0.69314718f, l, m);
}

// ---------------- MDN forward-algorithm scan ----------------
// 1 block (1 wave) per batch element; lane l owns s = 4l..4l+3 in registers.
__global__ __launch_bounds__(64)
void mdn_kernel(const float* __restrict__ logp, const int* __restrict__ mel_lens,
                const int* __restrict__ text_lens, float* __restrict__ alpha_out)
{
    const int b = blockIdx.x;
    const int l = threadIdx.x;
    const float* base = logp + (size_t)b * (TSEQ * TMEL);
    const int tmax = mel_lens[b] - 1;   // scan t = 1..tmax (tmax >= 511 per input spec)
    const int sf = text_lens[b] - 1;

    const float* r0 = base + (size_t)(4 * l + 0) * TMEL;
    const float* r1 = base + (size_t)(4 * l + 1) * TMEL;
    const float* r2 = base + (size_t)(4 * l + 2) * TMEL;
    const float* r3 = base + (size_t)(4 * l + 3) * TMEL;

    float a0 = (l == 0) ? base[0] : NEGV;
    float a1 = NEGV, a2 = NEGV, a3 = NEGV;

#define STEP(p0, p1, p2, p3) do { \
        float prev = __shfl_up(a3, 1); \
        if (l == 0) prev = NEGV; \
        float n0 = lae(a0 + 1e-4f, prev + 1e-4f) + (p0); \
        float n1 = lae(a1 + 1e-4f, a0 + 1e-4f) + (p1); \
        float n2 = lae(a2 + 1e-4f, a1 + 1e-4f) + (p2); \
        float n3 = lae(a3 + 1e-4f, a2 + 1e-4f) + (p3); \
        a0 = n0; a1 = n1; a2 = n2; a3 = n3; \
    } while (0)

    // chunk 0 covers t = 0..3; t=0 is the init column (skip), process t=1..3
    float4 c0 = *(const float4*)(r0);
    float4 c1 = *(const float4*)(r1);
    float4 c2 = *(const float4*)(r2);
    float4 c3 = *(const float4*)(r3);
    STEP(c0.y, c1.y, c2.y, c3.y);
    STEP(c0.z, c1.z, c2.z, c3.z);
    STEP(c0.w, c1.w, c2.w, c3.w);

    const int fullc = tmax >> 2;   // >= 127 for this input distribution
    // preload chunk 1
    c0 = *(const float4*)(r0 + 4);
    c1 = *(const float4*)(r1 + 4);
    c2 = *(const float4*)(r2 + 4);
    c3 = *(const float4*)(r3 + 4);
    for (int c = 1; c < fullc; ++c) {
        float4 n0 = *(const float4*)(r0 + 4 * (c + 1));
        float4 n1 = *(const float4*)(r1 + 4 * (c + 1));
        float4 n2 = *(const float4*)(r2 + 4 * (c + 1));
        float4 n3 = *(const float4*)(r3 + 4 * (c + 1));
        STEP(c0.x, c1.x, c2.x, c3.x);
        STEP(c0.y, c1.y, c2.y, c3.y);
        STEP(c0.z, c1.z, c2.z, c3.z);
        STEP(c0.w, c1.w, c2.w, c3.w);
        c0 = n0; c1 = n1; c2 = n2; c3 = n3;
    }
    // last chunk (c == fullc): t = 4*fullc .. tmax
    const int rem = tmax - 4 * fullc;
    STEP(c0.x, c1.x, c2.x, c3.x);
    if (rem >= 1) STEP(c0.y, c1.y, c2.y, c3.y);
    if (rem >= 2) STEP(c0.z, c1.z, c2.z, c3.z);
    if (rem >= 3) STEP(c0.w, c1.w, c2.w, c3.w);
#undef STEP

    int j = sf & 3;
    float v = (j == 0) ? a0 : (j == 1) ? a1 : (j == 2) ? a2 : a3;
    float res = __shfl(v, sf >> 2);
    if (l == 0) alpha_out[b] = res;
}

// ---------------- SSIM (separable 11x11 gaussian) + fused masked-MSE ----------------
#define TH 16
#define HALO 5
#define TR (TH + 2 * HALO)   // 26

__global__ __launch_bounds__(256)
void ssim_spec_kernel(const float* __restrict__ xg, const float* __restrict__ yg,
                      const int* __restrict__ lens,
                      float* __restrict__ ssim_part, float* __restrict__ spec_part)
{
    __shared__ float sx[TR][DDIM];
    __shared__ float sy[TR][DDIM];
    __shared__ float sv[5][TH][DDIM];
    __shared__ float wred[8];

    const int tid = threadIdx.x;
    const int blk = blockIdx.x;
    const int b  = blk >> 6;          // 64 row-blocks per image (1024/16)
    const int r0 = (blk & 63) * TH;
    const int len = lens[b];
    const float* px = xg + (size_t)b * TMEL * DDIM;
    const float* py = yg + (size_t)b * TMEL * DDIM;

    // gaussian taps (match reference: exp(-(i-5)^2/4.5), normalized)
    float g[11];
    {
        float s = 0.f;
#pragma unroll
        for (int i = 0; i < 11; ++i) {
            float t = (float)((i - 5) * (i - 5));
            g[i] = expf(-t / 4.5f);
            s += g[i];
        }
        float inv = 1.0f / s;
#pragma unroll
        for (int i = 0; i < 11; ++i) g[i] *= inv;
    }

    // load masked tile (zero pad rows outside image / beyond length); fuse spec MSE
    float aspec = 0.f;
    for (int i = tid; i < TR * DDIM; i += 256) {
        int rr = i / DDIM, cc = i - rr * DDIM;
        int gr = r0 - HALO + rr;
        float vx = 0.f, vy = 0.f;
        if (gr >= 0 && gr < len) {
            size_t off = (size_t)gr * DDIM + cc;
            vx = px[off]; vy = py[off];
        }
        sx[rr][cc] = vx; sy[rr][cc] = vy;
        if (rr >= HALO && rr < HALO + TH) {
            float d = vx - vy;
            aspec += d * d;
        }
    }
    __syncthreads();

    // vertical 11-tap conv of the 5 fields -> LDS
    for (int i = tid; i < TH * DDIM; i += 256) {
        int rr = i / DDIM, cc = i - rr * DDIM;
        float m1 = 0, m2 = 0, xx = 0, yy = 0, xy = 0;
#pragma unroll
        for (int k = 0; k < 11; ++k) {
            float w = g[k];
            float x = sx[rr + k][cc];
            float y = sy[rr + k][cc];
            m1 = fmaf(w, x, m1);
            m2 = fmaf(w, y, m2);
            xx = fmaf(w * x, x, xx);
            yy = fmaf(w * y, y, yy);
            xy = fmaf(w * x, y, xy);
        }
        sv[0][rr][cc] = m1; sv[1][rr][cc] = m2;
        sv[2][rr][cc] = xx; sv[3][rr][cc] = yy; sv[4][rr][cc] = xy;
    }
    __syncthreads();

    // horizontal 11-tap conv + ssim map
    float assim = 0.f;
    for (int i = tid; i < TH * DDIM; i += 256) {
        int rr = i / DDIM, cc = i - rr * DDIM;
        float m1 = 0, m2 = 0, xx = 0, yy = 0, xy = 0;
#pragma unroll
        for (int k = 0; k < 11; ++k) {
            int c2 = cc - HALO + k;
            if (c2 >= 0 && c2 < DDIM) {
                float w = g[k];
                m1 = fmaf(w, sv[0][rr][c2], m1);
                m2 = fmaf(w, sv[1][rr][c2], m2);
                xx = fmaf(w, sv[2][rr][c2], xx);
                yy = fmaf(w, sv[3][rr][c2], yy);
                xy = fmaf(w, sv[4][rr][c2], xy);
            }
        }
        float mu1s = m1 * m1, mu2s = m2 * m2, mu12 = m1 * m2;
        float s1 = xx - mu1s, s2 = yy - mu2s, s12 = xy - mu12;
        float num = (2.f * mu12 + 1e-4f) * (2.f * s12 + 9e-4f);
        float den = (mu1s + mu2s + 1e-4f) * (s1 + s2 + 9e-4f);
        assim += num / den;
    }

    // block-reduce both accumulators
#pragma unroll
    for (int o = 32; o > 0; o >>= 1) {
        assim += __shfl_down(assim, o);
        aspec += __shfl_down(aspec, o);
    }
    if ((tid & 63) == 0) { wred[tid >> 6] = assim; wred[4 + (tid >> 6)] = aspec; }
    __syncthreads();
    if (tid == 0) {
        ssim_part[blk] = wred[0] + wred[1] + wred[2] + wred[3];
        spec_part[blk] = wred[4] + wred[5] + wred[6] + wred[7];
    }
}

// ---------------- final reduction: dur loss, denominators, combine ----------------
__device__ __forceinline__ float block_sum(float v, float* sred, int tid) {
#pragma unroll
    for (int o = 32; o > 0; o >>= 1) v += __shfl_down(v, o);
    __syncthreads();
    if ((tid & 63) == 0) sred[tid >> 6] = v;
    __syncthreads();
    return sred[0] + sred[1] + sred[2] + sred[3];
}

__global__ __launch_bounds__(256)
void final_kernel(const float* __restrict__ ssim_part, const float* __restrict__ spec_part, int nparts,
                  const float* __restrict__ alpha_last,
                  const float* __restrict__ duro, const float* __restrict__ durt,
                  const int* __restrict__ dlens, const int* __restrict__ ilens,
                  float* __restrict__ out)
{
    __shared__ float sred[4];
    const int tid = threadIdx.x;
    float s_ssim = 0, s_spec = 0, s_alpha = 0, s_dur = 0, c_spec = 0, c_dur = 0;
    for (int i = tid; i < nparts; i += 256) { s_ssim += ssim_part[i]; s_spec += spec_part[i]; }
    for (int i = tid; i < NBATCH; i += 256) {
        s_alpha += alpha_last[i];
        int dl = dlens[i]; if (dl > TMEL) dl = TMEL;
        int il = ilens[i]; if (il > TSEQ) il = TSEQ;
        c_spec += (float)dl;
        c_dur  += (float)il;
    }
    for (int i = tid; i < NBATCH * TSEQ; i += 256) {
        int bb = i >> 8, ss = i & 255;
        if (ss < ilens[bb]) { float d = duro[i] - durt[i]; s_dur += d * d; }
    }
    float S_ssim  = block_sum(s_ssim, sred, tid);
    float S_spec  = block_sum(s_spec, sred, tid);
    float S_alpha = block_sum(s_alpha, sred, tid);
    float S_dur   = block_sum(s_dur, sred, tid);
    float C_spec  = block_sum(c_spec, sred, tid);
    float C_dur   = block_sum(c_dur, sred, tid);

    if (tid == 0) {
        float spec_loss = S_spec / (C_spec * (float)DDIM);
        float ssim_loss = 1.0f - S_ssim / (float)(NBATCH * TMEL * DDIM);
        float dur_loss  = S_dur / C_dur;
        float mdn_loss  = -(S_alpha / (float)NBATCH) / (float)TSEQ;
        out[0] = spec_loss + ssim_loss + dur_loss + mdn_loss;
        out[1] = spec_loss;
        out[2] = ssim_loss;
        out[3] = dur_loss;
        out[4] = mdn_loss;
    }
}

extern "C" void kernel_launch(void* const* d_in, const int* in_sizes, int n_in,
                              void* d_out, int out_size, void* d_ws, size_t ws_size,
                              hipStream_t stream) {
    const float* logp  = (const float*)d_in[0];
    const float* deco  = (const float*)d_in[1];
    const float* dect  = (const float*)d_in[2];
    const int*   dlens = (const int*)d_in[3];
    const float* duro  = (const float*)d_in[4];
    const float* durt  = (const float*)d_in[5];
    const int*   ilens = (const int*)d_in[6];
    // d_in[7] = step, d_in[8] = phase: unused by the loss

    float* ws     = (float*)d_ws;
    float* ssim_p = ws;            // 4096 floats
    float* spec_p = ws + 4096;     // 4096 floats
    float* alpha  = ws + 8192;     // 64 floats

    mdn_kernel<<<NBATCH, 64, 0, stream>>>(logp, dlens, ilens, alpha);
    ssim_spec_kernel<<<NBATCH * (TMEL / TH), 256, 0, stream>>>(deco, dect, dlens, ssim_p, spec_p);
    final_kernel<<<1, 256, 0, stream>>>(ssim_p, spec_p, NBATCH * (TMEL / TH), alpha,
                                        duro, durt, dlens, ilens, (float*)d_out);
}

// Round 2
// 243.326 us; speedup vs baseline: 1.0747x; 1.0747x over previous
//
#include <hip/hip_runtime.h>
#include <cmath>

#define TSEQ 256
#define TMEL 1024
#define DDIM 80
#define NBATCH 64
#define NEGV (-10000.0f)
#define LOG2E 1.44269504f
#define LN2 0.69314718f
#define NEGB (-10000.0f * LOG2E)
#define EPS2 (1e-4f * LOG2E)

// ===================== MDN scan on transposed layout =====================
// lpT[b][t][s] = (logp[b][s][t] + 1e-4) * log2e  (log2-domain, eps folded)
// 1 block = 1 wave per batch; lane l owns s = 4l..4l+3; 16-col double-buffered
// register prefetch; coalesced 1KB/wave column loads.
__global__ __launch_bounds__(64)
void mdn_scan_t(const float* __restrict__ lpT, const int* __restrict__ mel_lens,
                const int* __restrict__ text_lens, float* __restrict__ alpha_out)
{
    const int b = blockIdx.x;
    const int l = threadIdx.x;
    const int tmax = __builtin_amdgcn_readfirstlane(mel_lens[b] - 1); // 511..1023
    const int sf   = __builtin_amdgcn_readfirstlane(text_lens[b] - 1);
    const float4* col = (const float4*)(lpT + ((size_t)b << 18)) + l;

    float4 A[16], B[16];
    float a0, a1, a2, a3, s0, s1, s2, s3;

#define LOADCH(buf, t0) do { \
        _Pragma("unroll") \
        for (int j = 0; j < 16; ++j) buf[j] = col[(size_t)(((t0) + j) << 6)]; \
    } while (0)

    // log2-domain logaddexp: max(x,y) + log2(1 + 2^(-|x-y|))
#define STEP1(v, t) do { \
        float p3 = __shfl_up(a3, 1); \
        p3 = (l == 0) ? NEGB : p3; \
        float n0 = fmaxf(a0, p3) + __log2f(1.0f + exp2f(-fabsf(a0 - p3))) + (v).x; \
        float n1 = fmaxf(a1, a0) + __log2f(1.0f + exp2f(-fabsf(a1 - a0))) + (v).y; \
        float n2 = fmaxf(a2, a1) + __log2f(1.0f + exp2f(-fabsf(a2 - a1))) + (v).z; \
        float n3 = fmaxf(a3, a2) + __log2f(1.0f + exp2f(-fabsf(a3 - a2))) + (v).w; \
        a0 = n0; a1 = n1; a2 = n2; a3 = n3; \
        if ((t) == tmax) { s0 = a0; s1 = a1; s2 = a2; s3 = a3; } \
    } while (0)

#define STEPS16(buf, t0) do { \
        _Pragma("unroll") \
        for (int j = 0; j < 16; ++j) STEP1(buf[j], (t0) + j); \
    } while (0)

    LOADCH(A, 0);
    LOADCH(B, 16);
    a0 = (l == 0) ? (A[0].x - EPS2) : NEGB;   // init col has no lp/eps term
    a1 = a2 = a3 = NEGB;
    s0 = s1 = s2 = s3 = NEGB;
    _Pragma("unroll")
    for (int j = 1; j < 16; ++j) STEP1(A[j], j);

    for (int c = 16; c + 32 <= TMEL; c += 32) {
        LOADCH(A, c + 16);          // prefetch cols c+16..c+31
        STEPS16(B, c);              // steps c..c+15
        LOADCH(B, c + 32);          // prefetch cols c+32..c+47 (last iter reads pad)
        STEPS16(A, c + 16);         // steps c+16..c+31
    }
#undef LOADCH
#undef STEP1
#undef STEPS16

    int jj = sf & 3;
    float v = (jj == 0) ? s0 : (jj == 1) ? s1 : (jj == 2) ? s2 : s3;
    float res = __shfl(v, sf >> 2);
    if (l == 0) alpha_out[b] = res * LN2;     // back to natural log
}

// ===================== legacy direct-layout MDN (ws fallback) =====================
__device__ __forceinline__ float lae(float x, float y) {
    float m = fmaxf(x, y);
    float d = fabsf(x - y);
    float e = exp2f(d * -LOG2E);
    float l = __log2f(1.0f + e);
    return fmaf(LN2, l, m);
}

__global__ __launch_bounds__(64)
void mdn_kernel(const float* __restrict__ logp, const int* __restrict__ mel_lens,
                const int* __restrict__ text_lens, float* __restrict__ alpha_out)
{
    const int b = blockIdx.x;
    const int l = threadIdx.x;
    const float* base = logp + (size_t)b * (TSEQ * TMEL);
    const int tmax = mel_lens[b] - 1;
    const int sf = text_lens[b] - 1;

    const float* r0 = base + (size_t)(4 * l + 0) * TMEL;
    const float* r1 = base + (size_t)(4 * l + 1) * TMEL;
    const float* r2 = base + (size_t)(4 * l + 2) * TMEL;
    const float* r3 = base + (size_t)(4 * l + 3) * TMEL;

    float a0 = (l == 0) ? base[0] : NEGV;
    float a1 = NEGV, a2 = NEGV, a3 = NEGV;

#define STEP(p0, p1, p2, p3) do { \
        float prev = __shfl_up(a3, 1); \
        if (l == 0) prev = NEGV; \
        float n0 = lae(a0 + 1e-4f, prev + 1e-4f) + (p0); \
        float n1 = lae(a1 + 1e-4f, a0 + 1e-4f) + (p1); \
        float n2 = lae(a2 + 1e-4f, a1 + 1e-4f) + (p2); \
        float n3 = lae(a3 + 1e-4f, a2 + 1e-4f) + (p3); \
        a0 = n0; a1 = n1; a2 = n2; a3 = n3; \
    } while (0)

    float4 c0 = *(const float4*)(r0);
    float4 c1 = *(const float4*)(r1);
    float4 c2 = *(const float4*)(r2);
    float4 c3 = *(const float4*)(r3);
    STEP(c0.y, c1.y, c2.y, c3.y);
    STEP(c0.z, c1.z, c2.z, c3.z);
    STEP(c0.w, c1.w, c2.w, c3.w);

    const int fullc = tmax >> 2;
    c0 = *(const float4*)(r0 + 4);
    c1 = *(const float4*)(r1 + 4);
    c2 = *(const float4*)(r2 + 4);
    c3 = *(const float4*)(r3 + 4);
    for (int c = 1; c < fullc; ++c) {
        float4 n0 = *(const float4*)(r0 + 4 * (c + 1));
        float4 n1 = *(const float4*)(r1 + 4 * (c + 1));
        float4 n2 = *(const float4*)(r2 + 4 * (c + 1));
        float4 n3 = *(const float4*)(r3 + 4 * (c + 1));
        STEP(c0.x, c1.x, c2.x, c3.x);
        STEP(c0.y, c1.y, c2.y, c3.y);
        STEP(c0.z, c1.z, c2.z, c3.z);
        STEP(c0.w, c1.w, c2.w, c3.w);
        c0 = n0; c1 = n1; c2 = n2; c3 = n3;
    }
    const int rem = tmax - 4 * fullc;
    STEP(c0.x, c1.x, c2.x, c3.x);
    if (rem >= 1) STEP(c0.y, c1.y, c2.y, c3.y);
    if (rem >= 2) STEP(c0.z, c1.z, c2.z, c3.z);
    if (rem >= 3) STEP(c0.w, c1.w, c2.w, c3.w);
#undef STEP

    int j = sf & 3;
    float v = (j == 0) ? a0 : (j == 1) ? a1 : (j == 2) ? a2 : a3;
    float res = __shfl(v, sf >> 2);
    if (l == 0) alpha_out[b] = res;
}

// ===================== SSIM + fused masked-MSE =====================
#define TH 16
#define HALO 5
#define TR (TH + 2 * HALO)   // 26

struct SsimSmem {
    float sx[TR][DDIM];
    float sy[TR][DDIM];
    float sv[5][TH][DDIM];
    float wred[8];
};

__device__ __forceinline__ void ssim_body(SsimSmem* sm, int blk,
        const float* __restrict__ xg, const float* __restrict__ yg,
        const int* __restrict__ lens,
        float* __restrict__ ssim_part, float* __restrict__ spec_part)
{
    const int tid = threadIdx.x;
    const int b  = blk >> 6;
    const int r0 = (blk & 63) * TH;
    const int len = lens[b];
    const float* px = xg + (size_t)b * TMEL * DDIM;
    const float* py = yg + (size_t)b * TMEL * DDIM;

    float g[11];
    {
        float s = 0.f;
#pragma unroll
        for (int i = 0; i < 11; ++i) {
            float t = (float)((i - 5) * (i - 5));
            g[i] = expf(-t / 4.5f);
            s += g[i];
        }
        float inv = 1.0f / s;
#pragma unroll
        for (int i = 0; i < 11; ++i) g[i] *= inv;
    }

    float aspec = 0.f;
    for (int i = tid; i < TR * DDIM; i += 256) {
        int rr = i / DDIM, cc = i - rr * DDIM;
        int gr = r0 - HALO + rr;
        float vx = 0.f, vy = 0.f;
        if (gr >= 0 && gr < len) {
            size_t off = (size_t)gr * DDIM + cc;
            vx = px[off]; vy = py[off];
        }
        sm->sx[rr][cc] = vx; sm->sy[rr][cc] = vy;
        if (rr >= HALO && rr < HALO + TH) {
            float d = vx - vy;
            aspec += d * d;
        }
    }
    __syncthreads();

    for (int i = tid; i < TH * DDIM; i += 256) {
        int rr = i / DDIM, cc = i - rr * DDIM;
        float m1 = 0, m2 = 0, xx = 0, yy = 0, xy = 0;
#pragma unroll
        for (int k = 0; k < 11; ++k) {
            float w = g[k];
            float x = sm->sx[rr + k][cc];
            float y = sm->sy[rr + k][cc];
            m1 = fmaf(w, x, m1);
            m2 = fmaf(w, y, m2);
            xx = fmaf(w * x, x, xx);
            yy = fmaf(w * y, y, yy);
            xy = fmaf(w * x, y, xy);
        }
        sm->sv[0][rr][cc] = m1; sm->sv[1][rr][cc] = m2;
        sm->sv[2][rr][cc] = xx; sm->sv[3][rr][cc] = yy; sm->sv[4][rr][cc] = xy;
    }
    __syncthreads();

    float assim = 0.f;
    for (int i = tid; i < TH * DDIM; i += 256) {
        int rr = i / DDIM, cc = i - rr * DDIM;
        float m1 = 0, m2 = 0, xx = 0, yy = 0, xy = 0;
#pragma unroll
        for (int k = 0; k < 11; ++k) {
            int c2 = cc - HALO + k;
            if (c2 >= 0 && c2 < DDIM) {
                float w = g[k];
                m1 = fmaf(w, sm->sv[0][rr][c2], m1);
                m2 = fmaf(w, sm->sv[1][rr][c2], m2);
                xx = fmaf(w, sm->sv[2][rr][c2], xx);
                yy = fmaf(w, sm->sv[3][rr][c2], yy);
                xy = fmaf(w, sm->sv[4][rr][c2], xy);
            }
        }
        float mu1s = m1 * m1, mu2s = m2 * m2, mu12 = m1 * m2;
        float s1 = xx - mu1s, s2 = yy - mu2s, s12 = xy - mu12;
        float num = (2.f * mu12 + 1e-4f) * (2.f * s12 + 9e-4f);
        float den = (mu1s + mu2s + 1e-4f) * (s1 + s2 + 9e-4f);
        assim += num / den;
    }

#pragma unroll
    for (int o = 32; o > 0; o >>= 1) {
        assim += __shfl_down(assim, o);
        aspec += __shfl_down(aspec, o);
    }
    if ((tid & 63) == 0) { sm->wred[tid >> 6] = assim; sm->wred[4 + (tid >> 6)] = aspec; }
    __syncthreads();
    if (tid == 0) {
        ssim_part[blk] = sm->wred[0] + sm->wred[1] + sm->wred[2] + sm->wred[3];
        spec_part[blk] = sm->wred[4] + sm->wred[5] + sm->wred[6] + sm->wred[7];
    }
}

// ===================== transpose body (64x64 tile via LDS) =====================
__device__ __forceinline__ void transpose_body(float (*tp)[65], int blk,
        const float* __restrict__ logp, float* __restrict__ lpT)
{
    const int tid = threadIdx.x;
    const int b  = blk >> 6;
    const int tt = blk & 63;
    const int sbase = (tt >> 4) << 6;    // 0,64,128,192
    const int tbase = (tt & 15) << 6;    // 0..960
    const float* src = logp + ((size_t)b << 18);
    float* dst = lpT + ((size_t)b << 18);

#pragma unroll
    for (int i = 0; i < 4; ++i) {
        int idx = tid + (i << 8);
        int row = idx >> 4;              // s offset 0..63
        int c4  = (idx & 15) << 2;       // t offset 0..60
        float4 v = *(const float4*)(src + (size_t)(sbase + row) * TMEL + tbase + c4);
        tp[row][c4 + 0] = v.x; tp[row][c4 + 1] = v.y;
        tp[row][c4 + 2] = v.z; tp[row][c4 + 3] = v.w;
    }
    __syncthreads();
#pragma unroll
    for (int i = 0; i < 4; ++i) {
        int idx = tid + (i << 8);
        int trow = idx >> 4;             // t offset 0..63
        int sc4  = (idx & 15) << 2;      // s offset 0..60
        float4 v;
        v.x = fmaf(tp[sc4 + 0][trow], LOG2E, EPS2);
        v.y = fmaf(tp[sc4 + 1][trow], LOG2E, EPS2);
        v.z = fmaf(tp[sc4 + 2][trow], LOG2E, EPS2);
        v.w = fmaf(tp[sc4 + 3][trow], LOG2E, EPS2);
        *(float4*)(dst + (size_t)(tbase + trow) * TSEQ + sbase + sc4) = v;
    }
}

// ===================== fused K1: transpose blocks + ssim blocks =====================
#define SMEM_MAX ((sizeof(SsimSmem) > sizeof(float) * 64 * 65) ? sizeof(SsimSmem) : sizeof(float) * 64 * 65)

__global__ __launch_bounds__(256)
void fused1(const float* __restrict__ logp, float* __restrict__ lpT,
            const float* __restrict__ deco, const float* __restrict__ dect,
            const int* __restrict__ dlens,
            float* __restrict__ ssim_part, float* __restrict__ spec_part)
{
    __shared__ __align__(16) char smem[SMEM_MAX];
    if (blockIdx.x < NBATCH * 64) {
        transpose_body((float(*)[65])smem, blockIdx.x, logp, lpT);
    } else {
        ssim_body((SsimSmem*)smem, blockIdx.x - NBATCH * 64, deco, dect, dlens,
                  ssim_part, spec_part);
    }
}

__global__ __launch_bounds__(256)
void ssim_spec_kernel(const float* __restrict__ xg, const float* __restrict__ yg,
                      const int* __restrict__ lens,
                      float* __restrict__ ssim_part, float* __restrict__ spec_part)
{
    __shared__ __align__(16) char smem[sizeof(SsimSmem)];
    ssim_body((SsimSmem*)smem, blockIdx.x, xg, yg, lens, ssim_part, spec_part);
}

// ===================== final reduction =====================
__device__ __forceinline__ float block_sum(float v, float* sred, int tid) {
#pragma unroll
    for (int o = 32; o > 0; o >>= 1) v += __shfl_down(v, o);
    __syncthreads();
    if ((tid & 63) == 0) sred[tid >> 6] = v;
    __syncthreads();
    return sred[0] + sred[1] + sred[2] + sred[3];
}

__global__ __launch_bounds__(256)
void final_kernel(const float* __restrict__ ssim_part, const float* __restrict__ spec_part, int nparts,
                  const float* __restrict__ alpha_last,
                  const float* __restrict__ duro, const float* __restrict__ durt,
                  const int* __restrict__ dlens, const int* __restrict__ ilens,
                  float* __restrict__ out)
{
    __shared__ float sred[4];
    const int tid = threadIdx.x;
    float s_ssim = 0, s_spec = 0, s_alpha = 0, s_dur = 0, c_spec = 0, c_dur = 0;
    for (int i = tid; i < nparts; i += 256) { s_ssim += ssim_part[i]; s_spec += spec_part[i]; }
    for (int i = tid; i < NBATCH; i += 256) {
        s_alpha += alpha_last[i];
        int dl = dlens[i]; if (dl > TMEL) dl = TMEL;
        int il = ilens[i]; if (il > TSEQ) il = TSEQ;
        c_spec += (float)dl;
        c_dur  += (float)il;
    }
    for (int i = tid; i < NBATCH * TSEQ; i += 256) {
        int bb = i >> 8, ss = i & 255;
        if (ss < ilens[bb]) { float d = duro[i] - durt[i]; s_dur += d * d; }
    }
    float S_ssim  = block_sum(s_ssim, sred, tid);
    float S_spec  = block_sum(s_spec, sred, tid);
    float S_alpha = block_sum(s_alpha, sred, tid);
    float S_dur   = block_sum(s_dur, sred, tid);
    float C_spec  = block_sum(c_spec, sred, tid);
    float C_dur   = block_sum(c_dur, sred, tid);

    if (tid == 0) {
        float spec_loss = S_spec / (C_spec * (float)DDIM);
        float ssim_loss = 1.0f - S_ssim / (float)(NBATCH * TMEL * DDIM);
        float dur_loss  = S_dur / C_dur;
        float mdn_loss  = -(S_alpha / (float)NBATCH) / (float)TSEQ;
        out[0] = spec_loss + ssim_loss + dur_loss + mdn_loss;
        out[1] = spec_loss;
        out[2] = ssim_loss;
        out[3] = dur_loss;
        out[4] = mdn_loss;
    }
}

extern "C" void kernel_launch(void* const* d_in, const int* in_sizes, int n_in,
                              void* d_out, int out_size, void* d_ws, size_t ws_size,
                              hipStream_t stream) {
    const float* logp  = (const float*)d_in[0];
    const float* deco  = (const float*)d_in[1];
    const float* dect  = (const float*)d_in[2];
    const int*   dlens = (const int*)d_in[3];
    const float* duro  = (const float*)d_in[4];
    const float* durt  = (const float*)d_in[5];
    const int*   ilens = (const int*)d_in[6];

    const int nparts = NBATCH * (TMEL / TH);            // 4096 ssim blocks
    const size_t lpT_floats = (size_t)NBATCH * TMEL * TSEQ;   // 16.78M
    const size_t pad_floats = 16 * TSEQ;                       // prefetch overrun pad
    const size_t need_bytes = (lpT_floats + pad_floats + nparts * 2 + NBATCH) * sizeof(float);

    if (ws_size >= need_bytes) {
        float* lpT    = (float*)d_ws;
        float* ssim_p = lpT + lpT_floats + pad_floats;
        float* spec_p = ssim_p + nparts;
        float* alpha  = spec_p + nparts;

        fused1<<<NBATCH * 64 + nparts, 256, 0, stream>>>(logp, lpT, deco, dect, dlens,
                                                         ssim_p, spec_p);
        mdn_scan_t<<<NBATCH, 64, 0, stream>>>(lpT, dlens, ilens, alpha);
        final_kernel<<<1, 256, 0, stream>>>(ssim_p, spec_p, nparts, alpha,
                                            duro, durt, dlens, ilens, (float*)d_out);
    } else {
        float* ws     = (float*)d_ws;
        float* ssim_p = ws;
        float* spec_p = ws + nparts;
        float* alpha  = ws + 2 * nparts;

        mdn_kernel<<<NBATCH, 64, 0, stream>>>(logp, dlens, ilens, alpha);
        ssim_spec_kernel<<<nparts, 256, 0, stream>>>(deco, dect, dlens, ssim_p, spec_p);
        final_kernel<<<1, 256, 0, stream>>>(ssim_p, spec_p, nparts, alpha,
                                            duro, durt, dlens, ilens, (float*)d_out);
    }
}

// Round 3
// 182.936 us; speedup vs baseline: 1.4295x; 1.3301x over previous
//
#include <hip/hip_runtime.h>
#include <cmath>

#define TSEQ 256
#define TMEL 1024
#define DDIM 80
#define NBATCH 64

#define K2E 1.44269504089f
#define LN2f 0.693147181f
#define EPS2 (1e-4f * K2E)
#define NEGB (-10000.0f * K2E)
// deg-3 poly for log2(1+e), e in [0,1], z = 2e-1 ; max abs err ~1.1e-3
#define PB0 0.585518f
#define PB1 0.480528f
#define PB2 -0.0846029f
#define PB3 0.0192963f

#define TH 16
#define HALO 5
#define TR (TH + 2 * HALO)   // 26
#define SVW 96               // padded sv row: data at [8..87], zero pads [3..7],[88..92]

#define LDS_T_STRIDE 260     // floats per t-row (>=256, %32==4 -> conflict-free)
#define CHUNK_FLOATS (16 * LDS_T_STRIDE)

#define NB_MDN 64
#define NB_SSIM (NBATCH * (TMEL / TH))   // 4096
#define NB_DUR 8

struct SsimSmem {
    float sx[TR][DDIM];
    float sy[TR][DDIM];
    float sv[5][TH][SVW];
    float wred[8];
};
#define MDN_SMEM_BYTES (2 * CHUNK_FLOATS * 4)
#define SMEM_BYTES (sizeof(SsimSmem) > MDN_SMEM_BYTES ? sizeof(SsimSmem) : MDN_SMEM_BYTES)

// ---------------- MDN scan: direct-layout read, LDS transpose, poly-lae ----------------
__device__ __forceinline__ float lstep(float x, float y, float lp) {
    float d = x - y;
    float m = fmaxf(x, y);
    float e = exp2f(-fabsf(d));          // v_exp_f32 with -|.| modifiers
    float z = fmaf(2.0f, e, -1.0f);
    float t = fmaf(z, PB3, PB2);
    t = fmaf(z, t, PB1);
    t = fmaf(z, t, PB0);
    return (m + lp) + t;
}

__device__ __forceinline__ void mdn_body(float* lds,
        const float* __restrict__ logp, const int* __restrict__ mel_lens,
        const int* __restrict__ text_lens, float* __restrict__ alpha_out)
{
    if (threadIdx.x >= 64) return;       // wave 0 only; no __syncthreads in this path
    const int b = blockIdx.x;
    const int l = threadIdx.x;
    const int tmax = mel_lens[b] - 1;    // 511..1023
    const int sf   = text_lens[b] - 1;
    const int scol = l >> 2;             // s offset within 16-row group
    const float* pbase = logp + ((size_t)b << 18) + ((size_t)scol << 10) + ((l & 3) << 2);

    float4 GA[16], GB[16];
    float a0, a1, a2, a3;

#define SB __builtin_amdgcn_sched_barrier(0)

#define LOADC(buf, k) do { \
        const int _t0 = ((k) < 64) ? ((k) << 4) : 1008; \
        const float* _p = pbase + _t0; \
        _Pragma("unroll") \
        for (int i = 0; i < 16; ++i) buf[i] = *(const float4*)(_p + ((size_t)i << 14)); \
    } while (0)

#define WLDS(buf, p) do { \
        float* _d = lds + (p) * CHUNK_FLOATS + ((l & 3) << 2) * LDS_T_STRIDE + scol; \
        _Pragma("unroll") \
        for (int i = 0; i < 16; ++i) { \
            _d[(i << 4) + 0 * LDS_T_STRIDE] = fmaf(K2E, buf[i].x, EPS2); \
            _d[(i << 4) + 1 * LDS_T_STRIDE] = fmaf(K2E, buf[i].y, EPS2); \
            _d[(i << 4) + 2 * LDS_T_STRIDE] = fmaf(K2E, buf[i].z, EPS2); \
            _d[(i << 4) + 3 * LDS_T_STRIDE] = fmaf(K2E, buf[i].w, EPS2); \
        } } while (0)

#define CSTEP(p, j) do { \
        const float4 v = *(const float4*)(lds + (p) * CHUNK_FLOATS + (j) * LDS_T_STRIDE + (l << 2)); \
        float pr = __shfl_up(a3, 1); \
        pr = (l == 0) ? NEGB : pr; \
        float o0 = a0, o1 = a1, o2 = a2; \
        a0 = lstep(a0, pr, v.x); \
        a1 = lstep(a1, o0, v.y); \
        a2 = lstep(a2, o1, v.z); \
        a3 = lstep(a3, o2, v.w); \
    } while (0)

#define CCHUNK(p, jstart, jend) do { \
        _Pragma("unroll") \
        for (int j = 0; j < 16; ++j) { \
            if (j < (jstart)) continue; \
            if (j > (jend)) break; \
            CSTEP(p, j); \
        } } while (0)

    LOADC(GA, 0); LOADC(GB, 1); SB;
    WLDS(GA, 0); SB;
    {
        const float4 v0 = *(const float4*)(lds + (l << 2));   // t=0 row
        a0 = (l == 0) ? (v0.x - EPS2) : NEGB;                 // init: raw logp[0,0]*K
        a1 = NEGB; a2 = NEGB; a3 = NEGB;
    }
    const int klast = tmax >> 4;         // 31..63
    int k = 0;
    while (k + 2 <= klast) {
        LOADC(GA, k + 2); SB;
        WLDS(GB, 1); SB;
        CCHUNK(0, (k == 0) ? 1 : 0, 15); SB;
        LOADC(GB, k + 3); SB;
        WLDS(GA, 0); SB;
        CCHUNK(1, 0, 15); SB;
        k += 2;
    }
    if (k == klast) {
        CCHUNK(0, (k == 0) ? 1 : 0, tmax - (k << 4));
    } else {                              // klast == k+1
        WLDS(GB, 1); SB;
        CCHUNK(0, (k == 0) ? 1 : 0, 15); SB;
        CCHUNK(1, 0, tmax - (klast << 4));
    }
#undef SB
#undef LOADC
#undef WLDS
#undef CSTEP
#undef CCHUNK

    const int jj = sf & 3;
    float vv = (jj == 0) ? a0 : (jj == 1) ? a1 : (jj == 2) ? a2 : a3;
    float res = __shfl(vv, sf >> 2);
    if (l == 0) alpha_out[b] = res * LN2f;   // back to natural log
}

// ---------------- SSIM + fused masked spec-MSE ----------------
__device__ __forceinline__ float4 fma4(float w, const float4 a, float4 acc) {
    acc.x = fmaf(w, a.x, acc.x); acc.y = fmaf(w, a.y, acc.y);
    acc.z = fmaf(w, a.z, acc.z); acc.w = fmaf(w, a.w, acc.w); return acc;
}
__device__ __forceinline__ float4 mul4(const float4 a, const float4 b) {
    return make_float4(a.x * b.x, a.y * b.y, a.z * b.z, a.w * b.w);
}

__device__ __forceinline__ void ssim_body(SsimSmem* sm, int blk,
        const float* __restrict__ xg, const float* __restrict__ yg,
        const int* __restrict__ lens,
        float* __restrict__ ssim_part, float* __restrict__ spec_part)
{
    const int tid = threadIdx.x;
    const int b  = blk >> 6;
    const int r0 = (blk & 63) * TH;
    const int len = lens[b];
    const float* px = xg + (size_t)b * (TMEL * DDIM);
    const float* py = yg + (size_t)b * (TMEL * DDIM);

    float g[11];
    {
        float s = 0.f;
#pragma unroll
        for (int i = 0; i < 11; ++i) {
            float t = (float)((i - 5) * (i - 5));
            g[i] = expf(-t / 4.5f);
            s += g[i];
        }
        float inv = 1.0f / s;
#pragma unroll
        for (int i = 0; i < 11; ++i) g[i] *= inv;
    }

    // zero sv pad columns [3..7] and [88..92]
    for (int i = tid; i < 800; i += 256) {
        int f = i / 160;
        int r = (i / 10) % 16;
        int c = i % 10;
        int cc = (c < 5) ? (3 + c) : (83 + c);
        sm->sv[f][r][cc] = 0.f;
    }

    // masked float4 tile load + fused spec MSE
    float aspec = 0.f;
    for (int i = tid; i < TR * 20; i += 256) {
        int rr = i / 20, c4 = (i % 20) << 2;
        int gr = r0 - HALO + rr;
        float4 vx = make_float4(0.f, 0.f, 0.f, 0.f);
        float4 vy = make_float4(0.f, 0.f, 0.f, 0.f);
        if (gr >= 0 && gr < len) {
            vx = *(const float4*)(px + (size_t)gr * DDIM + c4);
            vy = *(const float4*)(py + (size_t)gr * DDIM + c4);
        }
        *(float4*)&sm->sx[rr][c4] = vx;
        *(float4*)&sm->sy[rr][c4] = vy;
        if (rr >= HALO && rr < HALO + TH) {
            float dx = vx.x - vy.x, dy = vx.y - vy.y, dz = vx.z - vy.z, dw = vx.w - vy.w;
            aspec += dx * dx + dy * dy + dz * dz + dw * dw;
        }
    }
    __syncthreads();

    // vertical 11-tap conv of 5 fields (float4 over columns)
    for (int i = tid; i < TH * 20; i += 256) {
        int rr = i / 20, c4 = (i % 20) << 2;
        float4 m1 = make_float4(0,0,0,0), m2 = m1, xx = m1, yy = m1, xy = m1;
#pragma unroll
        for (int kk = 0; kk < 11; ++kk) {
            float w = g[kk];
            const float4 x = *(const float4*)&sm->sx[rr + kk][c4];
            const float4 y = *(const float4*)&sm->sy[rr + kk][c4];
            m1 = fma4(w, x, m1);
            m2 = fma4(w, y, m2);
            xx = fma4(w, mul4(x, x), xx);
            yy = fma4(w, mul4(y, y), yy);
            xy = fma4(w, mul4(x, y), xy);
        }
        *(float4*)&sm->sv[0][rr][8 + c4] = m1;
        *(float4*)&sm->sv[1][rr][8 + c4] = m2;
        *(float4*)&sm->sv[2][rr][8 + c4] = xx;
        *(float4*)&sm->sv[3][rr][8 + c4] = yy;
        *(float4*)&sm->sv[4][rr][8 + c4] = xy;
    }
    __syncthreads();

    // horizontal 11-tap conv (sliding window, no branches) + ssim map
    float assim = 0.f;
    for (int i = tid; i < TH * 20; i += 256) {
        int rr = i / 20, c4 = (i % 20) << 2;
        float4 am[5];
        float wa[5], wb[5], wc[5], wd[5];
#pragma unroll
        for (int f = 0; f < 5; ++f) {
            am[f] = make_float4(0,0,0,0);
            wa[f] = sm->sv[f][rr][c4 + 3];
            wb[f] = sm->sv[f][rr][c4 + 4];
            wc[f] = sm->sv[f][rr][c4 + 5];
            wd[f] = sm->sv[f][rr][c4 + 6];
        }
#pragma unroll
        for (int kk = 0; kk < 11; ++kk) {
            float w = g[kk];
#pragma unroll
            for (int f = 0; f < 5; ++f) {
                am[f].x = fmaf(w, wa[f], am[f].x);
                am[f].y = fmaf(w, wb[f], am[f].y);
                am[f].z = fmaf(w, wc[f], am[f].z);
                am[f].w = fmaf(w, wd[f], am[f].w);
                wa[f] = wb[f]; wb[f] = wc[f]; wc[f] = wd[f];
                if (kk < 10) wd[f] = sm->sv[f][rr][c4 + 7 + kk];
            }
        }
#define SSIMC(C) { \
        float mu1 = am[0].C, mu2 = am[1].C, vxx = am[2].C, vyy = am[3].C, vxy = am[4].C; \
        float mu1s = mu1 * mu1, mu2s = mu2 * mu2, mu12 = mu1 * mu2; \
        float num = (2.f * mu12 + 1e-4f) * (2.f * (vxy - mu12) + 9e-4f); \
        float den = (mu1s + mu2s + 1e-4f) * ((vxx - mu1s) + (vyy - mu2s) + 9e-4f); \
        assim += num / den; }
        SSIMC(x) SSIMC(y) SSIMC(z) SSIMC(w)
#undef SSIMC
    }

#pragma unroll
    for (int o = 32; o > 0; o >>= 1) {
        assim += __shfl_down(assim, o);
        aspec += __shfl_down(aspec, o);
    }
    if ((tid & 63) == 0) { sm->wred[tid >> 6] = assim; sm->wred[4 + (tid >> 6)] = aspec; }
    __syncthreads();
    if (tid == 0) {
        ssim_part[blk] = sm->wred[0] + sm->wred[1] + sm->wred[2] + sm->wred[3];
        spec_part[blk] = sm->wred[4] + sm->wred[5] + sm->wred[6] + sm->wred[7];
    }
}

// ---------------- dur-loss partial sums ----------------
__device__ __forceinline__ void dur_body(float* sred, int blk2,
        const float* __restrict__ duro, const float* __restrict__ durt,
        const int* __restrict__ ilens, float* __restrict__ dur_part)
{
    const int tid = threadIdx.x;
    float s = 0.f;
    int i = blk2 * 2048 + tid;
#pragma unroll
    for (int it = 0; it < 8; ++it, i += 256) {
        int bb = i >> 8, ss = i & 255;
        float d = duro[i] - durt[i];
        s += (ss < ilens[bb]) ? d * d : 0.f;
    }
#pragma unroll
    for (int o = 32; o > 0; o >>= 1) s += __shfl_down(s, o);
    if ((tid & 63) == 0) sred[tid >> 6] = s;
    __syncthreads();
    if (tid == 0) dur_part[blk2] = sred[0] + sred[1] + sred[2] + sred[3];
}

// ---------------- fused main kernel ----------------
__global__ __launch_bounds__(256, 2)
void fused_main(const float* __restrict__ logp,
                const int* __restrict__ dlens, const int* __restrict__ ilens,
                const float* __restrict__ deco, const float* __restrict__ dect,
                const float* __restrict__ duro, const float* __restrict__ durt,
                float* __restrict__ alpha, float* __restrict__ ssim_p,
                float* __restrict__ spec_p, float* __restrict__ dur_p)
{
    __shared__ __align__(16) char smem[SMEM_BYTES];
    const int bx = blockIdx.x;
    if (bx < NB_MDN) {
        mdn_body((float*)smem, logp, dlens, ilens, alpha);
    } else if (bx < NB_MDN + NB_SSIM) {
        ssim_body((SsimSmem*)smem, bx - NB_MDN, deco, dect, dlens, ssim_p, spec_p);
    } else {
        dur_body((float*)smem, bx - NB_MDN - NB_SSIM, duro, durt, ilens, dur_p);
    }
}

// ---------------- final combine ----------------
__device__ __forceinline__ float block_sum(float v, float* sred, int tid) {
#pragma unroll
    for (int o = 32; o > 0; o >>= 1) v += __shfl_down(v, o);
    __syncthreads();
    if ((tid & 63) == 0) sred[tid >> 6] = v;
    __syncthreads();
    return sred[0] + sred[1] + sred[2] + sred[3];
}

__global__ __launch_bounds__(256)
void final_kernel(const float* __restrict__ ssim_p, const float* __restrict__ spec_p,
                  const float* __restrict__ dur_p, const float* __restrict__ alpha,
                  const int* __restrict__ dlens, const int* __restrict__ ilens,
                  float* __restrict__ out)
{
    __shared__ float sred[4];
    const int tid = threadIdx.x;
    float s_ssim = 0, s_spec = 0, s_alpha = 0, s_dur = 0, c_spec = 0, c_dur = 0;
    for (int i = tid; i < NB_SSIM; i += 256) { s_ssim += ssim_p[i]; s_spec += spec_p[i]; }
    if (tid < NB_DUR) s_dur = dur_p[tid];
    for (int i = tid; i < NBATCH; i += 256) {
        s_alpha += alpha[i];
        int dl = dlens[i]; if (dl > TMEL) dl = TMEL;
        int il = ilens[i]; if (il > TSEQ) il = TSEQ;
        c_spec += (float)dl;
        c_dur  += (float)il;
    }
    float S_ssim  = block_sum(s_ssim, sred, tid);
    float S_spec  = block_sum(s_spec, sred, tid);
    float S_alpha = block_sum(s_alpha, sred, tid);
    float S_dur   = block_sum(s_dur, sred, tid);
    float C_spec  = block_sum(c_spec, sred, tid);
    float C_dur   = block_sum(c_dur, sred, tid);

    if (tid == 0) {
        float spec_loss = S_spec / (C_spec * (float)DDIM);
        float ssim_loss = 1.0f - S_ssim / (float)(NBATCH * TMEL * DDIM);
        float dur_loss  = S_dur / C_dur;
        float mdn_loss  = -(S_alpha / (float)NBATCH) / (float)TSEQ;
        out[0] = spec_loss + ssim_loss + dur_loss + mdn_loss;
        out[1] = spec_loss;
        out[2] = ssim_loss;
        out[3] = dur_loss;
        out[4] = mdn_loss;
    }
}

extern "C" void kernel_launch(void* const* d_in, const int* in_sizes, int n_in,
                              void* d_out, int out_size, void* d_ws, size_t ws_size,
                              hipStream_t stream) {
    const float* logp  = (const float*)d_in[0];
    const float* deco  = (const float*)d_in[1];
    const float* dect  = (const float*)d_in[2];
    const int*   dlens = (const int*)d_in[3];
    const float* duro  = (const float*)d_in[4];
    const float* durt  = (const float*)d_in[5];
    const int*   ilens = (const int*)d_in[6];

    float* ws     = (float*)d_ws;
    float* ssim_p = ws;                       // 4096
    float* spec_p = ssim_p + NB_SSIM;         // 4096
    float* dur_p  = spec_p + NB_SSIM;         // 8
    float* alpha  = dur_p + NB_DUR;           // 64

    fused_main<<<NB_MDN + NB_SSIM + NB_DUR, 256, 0, stream>>>(
        logp, dlens, ilens, deco, dect, duro, durt, alpha, ssim_p, spec_p, dur_p);
    final_kernel<<<1, 256, 0, stream>>>(ssim_p, spec_p, dur_p, alpha,
                                        dlens, ilens, (float*)d_out);
}